// Round 1
// baseline (190.730 us; speedup 1.0000x reference)
//
#include <hip/hip_runtime.h>
#include <hip/hip_bf16.h>

#define S_LEN 4096
#define B_SZ 2
#define DM 1024
#define NH 16
#define DH 64

typedef __attribute__((ext_vector_type(8))) short short8;
typedef __attribute__((ext_vector_type(4))) float f32x4;

__device__ __forceinline__ ushort f2b(float f) {
  union { __hip_bfloat16 b; ushort u; } cv;
  cv.b = __float2bfloat16(f);
  return cv.u;
}

__device__ __forceinline__ void glds16(const ushort* g, ushort* l) {
  __builtin_amdgcn_global_load_lds(
      (const __attribute__((address_space(1))) void*)g,
      (__attribute__((address_space(3))) void*)l, 16, 0, 0);
}

// ---------------- fp32 -> bf16 convert (vectorized) ----------------
__global__ void cvt_kernel(const float* __restrict__ in, ushort* __restrict__ out, int n4) {
  for (int i = blockIdx.x * blockDim.x + threadIdx.x; i < n4;
       i += gridDim.x * blockDim.x) {
    float4 v = reinterpret_cast<const float4*>(in)[i];
    ushort4 o;
    o.x = f2b(v.x); o.y = f2b(v.y); o.z = f2b(v.z); o.w = f2b(v.w);
    reinterpret_cast<ushort4*>(out)[i] = o;
  }
}

// ---------------- bt-GEMM: C[m][n] = sum_k A[m][k]*W[n][k] ----------------
// OUTMODE 0: bf16 [M][N]; 1: bf16 per-head transposed [B][H][DH][S]; 2: f32 [M][N]
template <int OUTMODE>
__global__ void gemm_bt(const ushort* __restrict__ A, const ushort* __restrict__ W,
                        void* __restrict__ Cout, int M, int N, int K) {
  __shared__ ushort As[128 * 32];
  __shared__ ushort Bs[128 * 32];
  const int tid = threadIdx.x;
  const int lane = tid & 63;
  const int w = tid >> 6;
  const int wm = w >> 1, wn = w & 1;
  const int g = lane >> 4, lr = lane & 15;
  const int m0 = blockIdx.x * 128, n0 = blockIdx.y * 128;
  f32x4 acc[4][4] = {};

  const int srow = tid >> 2;        // 0..63
  const int scol = (tid & 3) * 8;   // bf16 element col
  const ushort* Abase = A + (size_t)(m0 + srow) * K + scol;
  const ushort* Wbase = W + (size_t)(n0 + srow) * K + scol;
  ushort* AsW = As + w * 512;  // wave-uniform LDS base (HW adds lane*16B)
  ushort* BsW = Bs + w * 512;

  for (int k0 = 0; k0 < K; k0 += 32) {
    __syncthreads();
    glds16(Abase + k0, AsW);
    glds16(Abase + k0 + (size_t)64 * K, AsW + 2048);
    glds16(Wbase + k0, BsW);
    glds16(Wbase + k0 + (size_t)64 * K, BsW + 2048);
    __syncthreads();
    short8 af[4], bfr[4];
#pragma unroll
    for (int m = 0; m < 4; m++)
      af[m] = *reinterpret_cast<const short8*>(As + (wm * 64 + m * 16 + lr) * 32 + g * 8);
#pragma unroll
    for (int n = 0; n < 4; n++)
      bfr[n] = *reinterpret_cast<const short8*>(Bs + (wn * 64 + n * 16 + lr) * 32 + g * 8);
#pragma unroll
    for (int m = 0; m < 4; m++)
#pragma unroll
      for (int n = 0; n < 4; n++)
        acc[m][n] = __builtin_amdgcn_mfma_f32_16x16x32_bf16(af[m], bfr[n], acc[m][n], 0, 0, 0);
  }

#pragma unroll
  for (int m = 0; m < 4; m++) {
    const int row0 = m0 + wm * 64 + m * 16 + g * 4;
#pragma unroll
    for (int n = 0; n < 4; n++) {
      const int col = n0 + wn * 64 + n * 16 + lr;
#pragma unroll
      for (int r = 0; r < 4; r++) {
        const int row = row0 + r;
        const float vv = acc[m][n][r];
        if (OUTMODE == 2) {
          reinterpret_cast<float*>(Cout)[(size_t)row * N + col] = vv;
        } else if (OUTMODE == 0) {
          reinterpret_cast<ushort*>(Cout)[(size_t)row * N + col] = f2b(vv);
        } else {
          const int b = row >> 12, s = row & 4095;
          const int h = col >> 6, dk = col & 63;
          reinterpret_cast<ushort*>(Cout)[(((size_t)(b * NH + h) * DH + dk) << 12) + s] = f2b(vv);
        }
      }
    }
  }
}

// ---------------- local attention (window |i-j|<=128) ----------------
// Qp,Kp: bf16 [B][S][DM] (head-major cols). Vt: bf16 [B][H][DH][S]. Ao: bf16 [B][S][DM].
__global__ void attn_local(const ushort* __restrict__ Qp, const ushort* __restrict__ Kp,
                           const ushort* __restrict__ Vt, ushort* __restrict__ Ao) {
  __shared__ ushort Ks[64 * 64];
  __shared__ ushort Vs[64 * 64];
  __shared__ ushort Ps[4][16 * 72];
  const int tid = threadIdx.x;
  const int lane = tid & 63;
  const int w = tid >> 6;
  const int g = lane >> 4, lr = lane & 15;
  const int bh = blockIdx.y, b = bh >> 4, h = bh & 15;
  const int q0 = blockIdx.x * 64;

  // Q fragments (A operand: row = lr, k = kk*32 + g*8 + j)
  const int qrow = q0 + w * 16 + lr;
  const ushort* qptr = Qp + ((size_t)b * S_LEN + qrow) * DM + h * DH;
  short8 qf[2];
  qf[0] = *reinterpret_cast<const short8*>(qptr + g * 8);
  qf[1] = *reinterpret_cast<const short8*>(qptr + 32 + g * 8);

  float m_r[4], l_r[4];
  f32x4 acc_o[4] = {};
#pragma unroll
  for (int r = 0; r < 4; r++) { m_r[r] = -1e30f; l_r[r] = 0.f; }

  const int sr = tid >> 3;          // 0..31 (row within 32-row half)
  const int scb = (tid & 7) * 16;   // physical byte col in 128B row

  const int t_lo = q0 >= 128 ? q0 - 128 : 0;
  const int t_hi = (q0 + 192) <= S_LEN ? (q0 + 192) : S_LEN;

  for (int k0 = t_lo; k0 < t_hi; k0 += 64) {
    __syncthreads();
#pragma unroll
    for (int i = 0; i < 2; i++) {
      const int row = i * 32 + sr;
      const int cb = scb ^ ((row & 7) << 4);  // pre-swizzled global source
      glds16(Kp + ((size_t)b * S_LEN + k0 + row) * DM + h * DH + cb / 2,
             Ks + i * 2048 + w * 512);
      glds16(Vt + (((size_t)bh * DH + row) << 12) + k0 + cb / 2,
             Vs + i * 2048 + w * 512);
    }
    __syncthreads();

    // QK^T: D[qrow][key], A=Q, B[k=dk][n=key] = K[key][dk]
    f32x4 sc[4] = {};
#pragma unroll
    for (int kk = 0; kk < 2; kk++) {
#pragma unroll
      for (int nt = 0; nt < 4; nt++) {
        const int kr = nt * 16 + lr;
        const int cb = (kk * 64 + g * 16) ^ ((kr & 7) << 4);
        short8 kf = *reinterpret_cast<const short8*>(
            reinterpret_cast<const char*>(Ks) + kr * 128 + cb);
        sc[nt] = __builtin_amdgcn_mfma_f32_16x16x32_bf16(qf[kk], kf, sc[nt], 0, 0, 0);
      }
    }
    // scale + window mask + row max
    float mx[4] = {-1e30f, -1e30f, -1e30f, -1e30f};
#pragma unroll
    for (int nt = 0; nt < 4; nt++) {
      const int key = k0 + nt * 16 + lr;
#pragma unroll
      for (int r = 0; r < 4; r++) {
        const int qr = q0 + w * 16 + g * 4 + r;
        int d = qr - key; d = d < 0 ? -d : d;
        float s = (d <= 128) ? sc[nt][r] * 0.125f : -1e9f;
        sc[nt][r] = s;
        mx[r] = fmaxf(mx[r], s);
      }
    }
#pragma unroll
    for (int r = 0; r < 4; r++) {
      mx[r] = fmaxf(mx[r], __shfl_xor(mx[r], 1));
      mx[r] = fmaxf(mx[r], __shfl_xor(mx[r], 2));
      mx[r] = fmaxf(mx[r], __shfl_xor(mx[r], 4));
      mx[r] = fmaxf(mx[r], __shfl_xor(mx[r], 8));
    }
    float fac[4], rs[4];
#pragma unroll
    for (int r = 0; r < 4; r++) {
      const float mn = fmaxf(m_r[r], mx[r]);
      fac[r] = __expf(m_r[r] - mn);
      m_r[r] = mn;
      rs[r] = 0.f;
    }
#pragma unroll
    for (int nt = 0; nt < 4; nt++)
#pragma unroll
      for (int r = 0; r < 4; r++) {
        const float p = __expf(sc[nt][r] - m_r[r]);
        sc[nt][r] = p;
        rs[r] += p;
      }
#pragma unroll
    for (int r = 0; r < 4; r++) {
      rs[r] += __shfl_xor(rs[r], 1);
      rs[r] += __shfl_xor(rs[r], 2);
      rs[r] += __shfl_xor(rs[r], 4);
      rs[r] += __shfl_xor(rs[r], 8);
      l_r[r] = l_r[r] * fac[r] + rs[r];
    }
#pragma unroll
    for (int nt = 0; nt < 4; nt++)
#pragma unroll
      for (int r = 0; r < 4; r++)
        acc_o[nt][r] *= fac[r];

    // P -> LDS (bf16, padded row 72 to dodge bank conflicts)
    ushort* myP = Ps[w];
#pragma unroll
    for (int nt = 0; nt < 4; nt++)
#pragma unroll
      for (int r = 0; r < 4; r++)
        myP[(g * 4 + r) * 72 + nt * 16 + lr] = f2b(sc[nt][r]);
    asm volatile("s_waitcnt lgkmcnt(0)" ::: "memory");
    __builtin_amdgcn_sched_barrier(0);

    // PV: D[qrow][dk], A=P (row=lr, k=key), B[k=key][n=dk] = Vt[dk][key]
#pragma unroll
    for (int kk = 0; kk < 2; kk++) {
      short8 pf = *reinterpret_cast<const short8*>(myP + lr * 72 + kk * 32 + g * 8);
#pragma unroll
      for (int nt = 0; nt < 4; nt++) {
        const int vr = nt * 16 + lr;
        const int cb = (kk * 64 + g * 16) ^ ((vr & 7) << 4);
        short8 vf = *reinterpret_cast<const short8*>(
            reinterpret_cast<const char*>(Vs) + vr * 128 + cb);
        acc_o[nt] = __builtin_amdgcn_mfma_f32_16x16x32_bf16(pf, vf, acc_o[nt], 0, 0, 0);
      }
    }
  }

  // epilogue: O / l  -> Ao[b][q][h*64+dk]
  const int qr0 = q0 + w * 16 + g * 4;
  ushort* orow = Ao + (size_t)b * S_LEN * DM + h * DH;
#pragma unroll
  for (int nt = 0; nt < 4; nt++)
#pragma unroll
    for (int r = 0; r < 4; r++)
      orow[(size_t)(qr0 + r) * DM + nt * 16 + lr] = f2b(acc_o[nt][r] / l_r[r]);
}

extern "C" void kernel_launch(void* const* d_in, const int* in_sizes, int n_in,
                              void* d_out, int out_size, void* d_ws, size_t ws_size,
                              hipStream_t stream) {
  const float* q  = (const float*)d_in[0];
  const float* k  = (const float*)d_in[1];
  const float* v  = (const float*)d_in[2];
  const float* wq = (const float*)d_in[3];
  const float* wk = (const float*)d_in[4];
  const float* wv = (const float*)d_in[5];
  const float* wo = (const float*)d_in[6];

  const size_t NX = (size_t)B_SZ * S_LEN * DM;  // 8388608
  const size_t NW = (size_t)DM * DM;            // 1048576
  if (ws_size < (7 * NX + 4 * NW) * sizeof(ushort)) return;

  ushort* ws  = (ushort*)d_ws;
  ushort* qb  = ws;
  ushort* kb  = qb + NX;
  ushort* vb  = kb + NX;
  ushort* wqb = vb + NX;
  ushort* wkb = wqb + NW;
  ushort* wvb = wkb + NW;
  ushort* wob = wvb + NW;
  ushort* Qp  = wob + NW;
  ushort* Kp  = Qp + NX;
  ushort* Vt  = Kp + NX;
  ushort* Ao  = Vt + NX;

  dim3 tb(256);
  cvt_kernel<<<dim3(1024), tb, 0, stream>>>(q, qb, (int)(NX / 4));
  cvt_kernel<<<dim3(1024), tb, 0, stream>>>(k, kb, (int)(NX / 4));
  cvt_kernel<<<dim3(1024), tb, 0, stream>>>(v, vb, (int)(NX / 4));
  cvt_kernel<<<dim3(256), tb, 0, stream>>>(wq, wqb, (int)(NW / 4));
  cvt_kernel<<<dim3(256), tb, 0, stream>>>(wk, wkb, (int)(NW / 4));
  cvt_kernel<<<dim3(256), tb, 0, stream>>>(wv, wvb, (int)(NW / 4));
  cvt_kernel<<<dim3(256), tb, 0, stream>>>(wo, wob, (int)(NW / 4));

  dim3 gg(64, 8);
  gemm_bt<0><<<gg, tb, 0, stream>>>(qb, wqb, Qp, 8192, 1024, 1024);
  gemm_bt<0><<<gg, tb, 0, stream>>>(kb, wkb, Kp, 8192, 1024, 1024);
  gemm_bt<1><<<gg, tb, 0, stream>>>(vb, wvb, Vt, 8192, 1024, 1024);

  attn_local<<<dim3(64, 32), tb, 0, stream>>>(Qp, Kp, Vt, Ao);

  gemm_bt<2><<<gg, tb, 0, stream>>>(Ao, wob, (float*)d_out, 8192, 1024, 1024);
}

// Round 2
// 189.106 us; speedup vs baseline: 1.0086x; 1.0086x over previous
//
#include <hip/hip_runtime.h>
#include <hip/hip_bf16.h>

#define S_LEN 4096
#define B_SZ 2
#define DM 1024
#define NH 16
#define DH 64

typedef __attribute__((ext_vector_type(8))) short short8;
typedef __attribute__((ext_vector_type(4))) float f32x4;

__device__ __forceinline__ ushort f2b(float f) {
  union { __hip_bfloat16 b; ushort u; } cv;
  cv.b = __float2bfloat16(f);
  return cv.u;
}

__device__ __forceinline__ void glds16(const ushort* g, ushort* l) {
  __builtin_amdgcn_global_load_lds(
      (const __attribute__((address_space(1))) void*)g,
      (__attribute__((address_space(3))) void*)l, 16, 0, 0);
}

// ---------------- merged fp32 -> bf16 convert ----------------
// dst layout: qb,kb,vb,wqb,wkb,wvb,wob contiguous (in float4/ushort4 units)
__global__ void cvt_all(const float* __restrict__ q, const float* __restrict__ k,
                        const float* __restrict__ v, const float* __restrict__ wq,
                        const float* __restrict__ wk, const float* __restrict__ wv,
                        const float* __restrict__ wo, ushort* __restrict__ dst) {
  const int NX4 = 2097152;  // 8M/4
  const int NW4 = 262144;   // 1M/4
  const int total = 3 * NX4 + 4 * NW4;
  for (int i = blockIdx.x * blockDim.x + threadIdx.x; i < total;
       i += gridDim.x * blockDim.x) {
    const float* s;
    int j;
    if (i < NX4) { s = q; j = i; }
    else if (i < 2 * NX4) { s = k; j = i - NX4; }
    else if (i < 3 * NX4) { s = v; j = i - 2 * NX4; }
    else {
      int t = i - 3 * NX4;
      int wsel = t >> 18;
      j = t & (NW4 - 1);
      s = wsel == 0 ? wq : wsel == 1 ? wk : wsel == 2 ? wv : wo;
    }
    float4 val = reinterpret_cast<const float4*>(s)[j];
    ushort4 o;
    o.x = f2b(val.x); o.y = f2b(val.y); o.z = f2b(val.z); o.w = f2b(val.w);
    reinterpret_cast<ushort4*>(dst)[i] = o;
  }
}

// swizzled LDS read: logical (row, byte-col) -> physical (XOR row bits 2,3 into col bits 5,6)
__device__ __forceinline__ short8 ldsrd(const ushort* base, int row, int cb) {
  const int pcb = cb ^ ((row & 4) << 3) ^ ((row & 8) << 3);
  return *reinterpret_cast<const short8*>(
      reinterpret_cast<const char*>(base) + row * 128 + pcb);
}

// ---------------- phased bt-GEMM: C[m][n] = sum_k A[m][k]*W[n][k] ----------------
// BM=128, BN=256, BK=64, 8 waves (wm 0..1 x wn 0..3), per-wave 64x64 out.
// MODE 0: QKV fused (blockIdx.y: 0-3 Q, 4-7 K, 8-11 V->transposed). MODE 2: f32 out.
template <int MODE>
__launch_bounds__(512, 2)
__global__ void gemm8(const ushort* __restrict__ A0, const ushort* __restrict__ A1,
                      const ushort* __restrict__ A2, const ushort* __restrict__ W0,
                      const ushort* __restrict__ W1, const ushort* __restrict__ W2,
                      void* __restrict__ O0, void* __restrict__ O1,
                      void* __restrict__ O2) {
  __shared__ ushort As[2][128 * 64];  // 32 KB
  __shared__ ushort Bs[2][256 * 64];  // 64 KB
  const int tid = threadIdx.x;
  const int lane = tid & 63, w = tid >> 6;
  const int wm = w & 1, wn = w >> 1;
  const int g = lane >> 4, lr = lane & 15;
  const int m0 = blockIdx.x * 128;
  const int ysel = (MODE == 0) ? (blockIdx.y >> 2) : 0;
  const ushort* A = (MODE == 0) ? (ysel == 0 ? A0 : ysel == 1 ? A1 : A2) : A0;
  const ushort* W = (MODE == 0) ? (ysel == 0 ? W0 : ysel == 1 ? W1 : W2) : W0;
  const int n0w = ((MODE == 0) ? (blockIdx.y & 3) : blockIdx.y) * 256;

  // staging geometry: thread -> (row_r, 16B chunk); pre-swizzled global source col
  const int row_r = tid >> 3;
  const int cb_log = ((tid & 7) * 16) ^ ((row_r & 4) << 3) ^ ((row_r & 8) << 3);
  const ushort* Asrc = A + (size_t)(m0 + row_r) * DM + (cb_log >> 1);
  const ushort* Wsrc = W + (size_t)(n0w + row_r) * DM + (cb_log >> 1);

#define STAGE_A(buf, kt)                                       \
  { const int kq = (kt) * 64;                                  \
    glds16(Asrc + kq, &As[buf][w * 512]);                      \
    glds16(Asrc + (size_t)64 * DM + kq, &As[buf][4096 + w * 512]); }
#define STAGE_B(buf, kt)                                       \
  { const int kq = (kt) * 64;                                  \
    glds16(Wsrc + kq, &Bs[buf][w * 512]);                      \
    glds16(Wsrc + (size_t)64 * DM + kq, &Bs[buf][4096 + w * 512]);   \
    glds16(Wsrc + (size_t)128 * DM + kq, &Bs[buf][8192 + w * 512]);  \
    glds16(Wsrc + (size_t)192 * DM + kq, &Bs[buf][12288 + w * 512]); }

  f32x4 acc[4][4] = {};
  short8 af[4][2], bf0[2][2], bf1[2][2];

  // prologue: tile0 A+B, tile1 A. vmcnt(2) leaves tile1-A in flight.
  STAGE_A(0, 0);
  STAGE_B(0, 0);
  STAGE_A(1, 1);
  asm volatile("s_waitcnt vmcnt(2)" ::: "memory");
  __builtin_amdgcn_s_barrier();
  __builtin_amdgcn_sched_barrier(0);

  for (int t = 0; t < 16; ++t) {
    const int buf = t & 1;
    // ---- phase 1: read all A + B cols [0,32); stage next tile's B ----
#pragma unroll
    for (int m = 0; m < 4; m++)
#pragma unroll
      for (int kk = 0; kk < 2; kk++)
        af[m][kk] = ldsrd(&As[buf][0], wm * 64 + m * 16 + lr, kk * 64 + g * 16);
#pragma unroll
    for (int n = 0; n < 2; n++)
#pragma unroll
      for (int kk = 0; kk < 2; kk++)
        bf0[n][kk] = ldsrd(&Bs[buf][0], wn * 64 + n * 16 + lr, kk * 64 + g * 16);
    {
      int tn = t + 1; if (tn > 15) tn = 15;
      STAGE_B(buf ^ 1, tn);
    }
    __builtin_amdgcn_sched_barrier(0);
    __builtin_amdgcn_s_barrier();
    asm volatile("s_waitcnt lgkmcnt(0)" ::: "memory");
    __builtin_amdgcn_sched_barrier(0);
    __builtin_amdgcn_s_setprio(1);
#pragma unroll
    for (int m = 0; m < 4; m++)
#pragma unroll
      for (int n = 0; n < 2; n++)
#pragma unroll
        for (int kk = 0; kk < 2; kk++)
          acc[m][n] = __builtin_amdgcn_mfma_f32_16x16x32_bf16(af[m][kk], bf0[n][kk],
                                                              acc[m][n], 0, 0, 0);
    __builtin_amdgcn_s_setprio(0);
    __builtin_amdgcn_sched_barrier(0);
    __builtin_amdgcn_s_barrier();
    __builtin_amdgcn_sched_barrier(0);
    // ---- phase 2: read B cols [32,64); stage tile t+2's A; counted vmcnt ----
#pragma unroll
    for (int n = 0; n < 2; n++)
#pragma unroll
      for (int kk = 0; kk < 2; kk++)
        bf1[n][kk] = ldsrd(&Bs[buf][0], wn * 64 + 32 + n * 16 + lr, kk * 64 + g * 16);
    {
      int tn = t + 2; if (tn > 15) tn = 15;
      STAGE_A(buf, tn);
    }
    asm volatile("s_waitcnt vmcnt(2)" ::: "memory");
    __builtin_amdgcn_sched_barrier(0);
    __builtin_amdgcn_s_barrier();
    asm volatile("s_waitcnt lgkmcnt(0)" ::: "memory");
    __builtin_amdgcn_sched_barrier(0);
    __builtin_amdgcn_s_setprio(1);
#pragma unroll
    for (int m = 0; m < 4; m++)
#pragma unroll
      for (int n = 0; n < 2; n++)
#pragma unroll
        for (int kk = 0; kk < 2; kk++)
          acc[m][2 + n] = __builtin_amdgcn_mfma_f32_16x16x32_bf16(af[m][kk], bf1[n][kk],
                                                                  acc[m][2 + n], 0, 0, 0);
    __builtin_amdgcn_s_setprio(0);
    __builtin_amdgcn_sched_barrier(0);
    __builtin_amdgcn_s_barrier();
    __builtin_amdgcn_sched_barrier(0);
  }
#undef STAGE_A
#undef STAGE_B

  // epilogue
  const int colBase = ((MODE == 0) ? (blockIdx.y & 3) : blockIdx.y) * 256 + wn * 64;
#pragma unroll
  for (int m = 0; m < 4; m++) {
    const int row0 = m0 + wm * 64 + m * 16 + g * 4;
#pragma unroll
    for (int nn = 0; nn < 4; nn++) {
      const int col = colBase + nn * 16 + lr;
#pragma unroll
      for (int r = 0; r < 4; r++) {
        const int row = row0 + r;
        const float vv = acc[m][nn][r];
        if (MODE == 2) {
          reinterpret_cast<float*>(O0)[(size_t)row * DM + col] = vv;
        } else {
          if (ysel == 0) {
            reinterpret_cast<ushort*>(O0)[(size_t)row * DM + col] = f2b(vv);
          } else if (ysel == 1) {
            reinterpret_cast<ushort*>(O1)[(size_t)row * DM + col] = f2b(vv);
          } else {
            const int b = row >> 12, s = row & 4095;
            const int h = col >> 6, dk = col & 63;
            reinterpret_cast<ushort*>(O2)[(((size_t)(b * NH + h) * DH + dk) << 12) + s] =
                f2b(vv);
          }
        }
      }
    }
  }
}

// ---------------- local attention (window |i-j|<=128) ----------------
__global__ void attn_local(const ushort* __restrict__ Qp, const ushort* __restrict__ Kp,
                           const ushort* __restrict__ Vt, ushort* __restrict__ Ao) {
  __shared__ ushort Ks[64 * 64];
  __shared__ ushort Vs[64 * 64];
  __shared__ ushort Ps[4][16 * 72];
  const int tid = threadIdx.x;
  const int lane = tid & 63;
  const int w = tid >> 6;
  const int g = lane >> 4, lr = lane & 15;
  const int bh = blockIdx.y, b = bh >> 4, h = bh & 15;
  const int q0 = blockIdx.x * 64;

  const int qrow = q0 + w * 16 + lr;
  const ushort* qptr = Qp + ((size_t)b * S_LEN + qrow) * DM + h * DH;
  short8 qf[2];
  qf[0] = *reinterpret_cast<const short8*>(qptr + g * 8);
  qf[1] = *reinterpret_cast<const short8*>(qptr + 32 + g * 8);

  float m_r[4], l_r[4];
  f32x4 acc_o[4] = {};
#pragma unroll
  for (int r = 0; r < 4; r++) { m_r[r] = -1e30f; l_r[r] = 0.f; }

  const int sr = tid >> 3;
  const int scb = (tid & 7) * 16;

  const int t_lo = q0 >= 128 ? q0 - 128 : 0;
  const int t_hi = (q0 + 192) <= S_LEN ? (q0 + 192) : S_LEN;

  for (int k0 = t_lo; k0 < t_hi; k0 += 64) {
    __syncthreads();
#pragma unroll
    for (int i = 0; i < 2; i++) {
      const int row = i * 32 + sr;
      const int cb = scb ^ ((row & 7) << 4);
      glds16(Kp + ((size_t)b * S_LEN + k0 + row) * DM + h * DH + cb / 2,
             Ks + i * 2048 + w * 512);
      glds16(Vt + (((size_t)bh * DH + row) << 12) + k0 + cb / 2,
             Vs + i * 2048 + w * 512);
    }
    __syncthreads();

    f32x4 sc[4] = {};
#pragma unroll
    for (int kk = 0; kk < 2; kk++) {
#pragma unroll
      for (int nt = 0; nt < 4; nt++) {
        const int kr = nt * 16 + lr;
        const int cb = (kk * 64 + g * 16) ^ ((kr & 7) << 4);
        short8 kf = *reinterpret_cast<const short8*>(
            reinterpret_cast<const char*>(Ks) + kr * 128 + cb);
        sc[nt] = __builtin_amdgcn_mfma_f32_16x16x32_bf16(qf[kk], kf, sc[nt], 0, 0, 0);
      }
    }
    float mx[4] = {-1e30f, -1e30f, -1e30f, -1e30f};
#pragma unroll
    for (int nt = 0; nt < 4; nt++) {
      const int key = k0 + nt * 16 + lr;
#pragma unroll
      for (int r = 0; r < 4; r++) {
        const int qr = q0 + w * 16 + g * 4 + r;
        int d = qr - key; d = d < 0 ? -d : d;
        float s = (d <= 128) ? sc[nt][r] * 0.125f : -1e9f;
        sc[nt][r] = s;
        mx[r] = fmaxf(mx[r], s);
      }
    }
#pragma unroll
    for (int r = 0; r < 4; r++) {
      mx[r] = fmaxf(mx[r], __shfl_xor(mx[r], 1));
      mx[r] = fmaxf(mx[r], __shfl_xor(mx[r], 2));
      mx[r] = fmaxf(mx[r], __shfl_xor(mx[r], 4));
      mx[r] = fmaxf(mx[r], __shfl_xor(mx[r], 8));
    }
    float fac[4], rs[4];
#pragma unroll
    for (int r = 0; r < 4; r++) {
      const float mn = fmaxf(m_r[r], mx[r]);
      fac[r] = __expf(m_r[r] - mn);
      m_r[r] = mn;
      rs[r] = 0.f;
    }
#pragma unroll
    for (int nt = 0; nt < 4; nt++)
#pragma unroll
      for (int r = 0; r < 4; r++) {
        const float p = __expf(sc[nt][r] - m_r[r]);
        sc[nt][r] = p;
        rs[r] += p;
      }
#pragma unroll
    for (int r = 0; r < 4; r++) {
      rs[r] += __shfl_xor(rs[r], 1);
      rs[r] += __shfl_xor(rs[r], 2);
      rs[r] += __shfl_xor(rs[r], 4);
      rs[r] += __shfl_xor(rs[r], 8);
      l_r[r] = l_r[r] * fac[r] + rs[r];
    }
#pragma unroll
    for (int nt = 0; nt < 4; nt++)
#pragma unroll
      for (int r = 0; r < 4; r++)
        acc_o[nt][r] *= fac[r];

    ushort* myP = Ps[w];
#pragma unroll
    for (int nt = 0; nt < 4; nt++)
#pragma unroll
      for (int r = 0; r < 4; r++)
        myP[(g * 4 + r) * 72 + nt * 16 + lr] = f2b(sc[nt][r]);
    asm volatile("s_waitcnt lgkmcnt(0)" ::: "memory");
    __builtin_amdgcn_sched_barrier(0);

#pragma unroll
    for (int kk = 0; kk < 2; kk++) {
      short8 pf = *reinterpret_cast<const short8*>(myP + lr * 72 + kk * 32 + g * 8);
#pragma unroll
      for (int nt = 0; nt < 4; nt++) {
        const int vr = nt * 16 + lr;
        const int cb = (kk * 64 + g * 16) ^ ((vr & 7) << 4);
        short8 vf = *reinterpret_cast<const short8*>(
            reinterpret_cast<const char*>(Vs) + vr * 128 + cb);
        acc_o[nt] = __builtin_amdgcn_mfma_f32_16x16x32_bf16(pf, vf, acc_o[nt], 0, 0, 0);
      }
    }
  }

  const int qr0 = q0 + w * 16 + g * 4;
  ushort* orow = Ao + (size_t)b * S_LEN * DM + h * DH;
#pragma unroll
  for (int nt = 0; nt < 4; nt++)
#pragma unroll
    for (int r = 0; r < 4; r++)
      orow[(size_t)(qr0 + r) * DM + nt * 16 + lr] = f2b(acc_o[nt][r] / l_r[r]);
}

extern "C" void kernel_launch(void* const* d_in, const int* in_sizes, int n_in,
                              void* d_out, int out_size, void* d_ws, size_t ws_size,
                              hipStream_t stream) {
  const float* q  = (const float*)d_in[0];
  const float* k  = (const float*)d_in[1];
  const float* v  = (const float*)d_in[2];
  const float* wq = (const float*)d_in[3];
  const float* wk = (const float*)d_in[4];
  const float* wv = (const float*)d_in[5];
  const float* wo = (const float*)d_in[6];

  const size_t NX = (size_t)B_SZ * S_LEN * DM;  // 8388608
  const size_t NW = (size_t)DM * DM;            // 1048576
  if (ws_size < (7 * NX + 4 * NW) * sizeof(ushort)) return;

  ushort* ws  = (ushort*)d_ws;
  ushort* qb  = ws;
  ushort* kb  = qb + NX;
  ushort* vb  = kb + NX;
  ushort* wqb = vb + NX;
  ushort* wkb = wqb + NW;
  ushort* wvb = wkb + NW;
  ushort* wob = wvb + NW;
  ushort* Qp  = wob + NW;
  ushort* Kp  = Qp + NX;
  ushort* Vt  = Kp + NX;
  ushort* Ao  = Vt + NX;

  cvt_all<<<dim3(2048), dim3(256), 0, stream>>>(q, k, v, wq, wk, wv, wo, ws);

  gemm8<0><<<dim3(64, 12), dim3(512), 0, stream>>>(qb, kb, vb, wqb, wkb, wvb,
                                                   Qp, Kp, Vt);

  attn_local<<<dim3(64, 32), dim3(256), 0, stream>>>(Qp, Kp, Vt, Ao);

  gemm8<2><<<dim3(64, 4), dim3(512), 0, stream>>>(Ao, Ao, Ao, wob, wob, wob,
                                                  d_out, d_out, d_out);
}

// Round 3
// 173.596 us; speedup vs baseline: 1.0987x; 1.0893x over previous
//
#include <hip/hip_runtime.h>
#include <hip/hip_bf16.h>

#define S_LEN 4096
#define B_SZ 2
#define DM 1024
#define NH 16
#define DH 64

typedef __attribute__((ext_vector_type(8))) short short8;
typedef __attribute__((ext_vector_type(4))) float f32x4;

__device__ __forceinline__ ushort f2b(float f) {
  union { __hip_bfloat16 b; ushort u; } cv;
  cv.b = __float2bfloat16(f);
  return cv.u;
}

__device__ __forceinline__ void glds16(const ushort* g, ushort* l) {
  __builtin_amdgcn_global_load_lds(
      (const __attribute__((address_space(1))) void*)g,
      (__attribute__((address_space(3))) void*)l, 16, 0, 0);
}

// ---------------- merged fp32 -> bf16 convert ----------------
__global__ void cvt_all(const float* __restrict__ q, const float* __restrict__ k,
                        const float* __restrict__ v, const float* __restrict__ wq,
                        const float* __restrict__ wk, const float* __restrict__ wv,
                        const float* __restrict__ wo, ushort* __restrict__ dst) {
  const int NX4 = 2097152;  // 8M/4
  const int NW4 = 262144;   // 1M/4
  const int total = 3 * NX4 + 4 * NW4;
  for (int i = blockIdx.x * blockDim.x + threadIdx.x; i < total;
       i += gridDim.x * blockDim.x) {
    const float* s;
    int j;
    if (i < NX4) { s = q; j = i; }
    else if (i < 2 * NX4) { s = k; j = i - NX4; }
    else if (i < 3 * NX4) { s = v; j = i - 2 * NX4; }
    else {
      int t = i - 3 * NX4;
      int wsel = t >> 18;
      j = t & (NW4 - 1);
      s = wsel == 0 ? wq : wsel == 1 ? wk : wsel == 2 ? wv : wo;
    }
    float4 val = reinterpret_cast<const float4*>(s)[j];
    ushort4 o;
    o.x = f2b(val.x); o.y = f2b(val.y); o.z = f2b(val.z); o.w = f2b(val.w);
    reinterpret_cast<ushort4*>(dst)[i] = o;
  }
}

// swizzled LDS read: XOR row bits 0-2 into byte-col bits 4-6 (r268-proven)
__device__ __forceinline__ short8 ldsrd(const ushort* base, int row, int cb) {
  const int pcb = cb ^ ((row & 7) << 4);
  return *reinterpret_cast<const short8*>(
      reinterpret_cast<const char*>(base) + row * 128 + pcb);
}

// ---------------- counted-vmcnt phased bt-GEMM ----------------
// C[m][n] = sum_k A[m][k]*W[n][k].  BM=256, BN=256, BK=64, 512 threads.
// 8 waves, each owns 256 rows x 32 cols. Phase p (0..3) computes M-frags
// 4p..4p+3. Stage order per tile: Bh0,Bh1,Ah0,Ah1 -> vmcnt(4)@ph1 end
// (guarantees current tile's Ah1 before ph2), vmcnt(2)@ph3 end (guarantees
// next tile's Bh0/Bh1/Ah0, leaves its Ah1 in flight). Never drains to 0.
// MODE 0: QKV fused (blockIdx.y: y>>2 selects mat; V written transposed).
// MODE 2: f32 out.
template <int MODE>
__launch_bounds__(512, 2)
__global__ void gemm8(const ushort* __restrict__ A0, const ushort* __restrict__ A1,
                      const ushort* __restrict__ A2, const ushort* __restrict__ W0,
                      const ushort* __restrict__ W1, const ushort* __restrict__ W2,
                      void* __restrict__ O0, void* __restrict__ O1,
                      void* __restrict__ O2) {
  __shared__ ushort As[2][16384];  // 256x64 per buf, 64 KB total
  __shared__ ushort Bs[2][16384];  // 64 KB total
  const int tid = threadIdx.x;
  const int lane = tid & 63, w = tid >> 6;
  const int g = lane >> 4, lr = lane & 15;
  const int m0 = blockIdx.x * 256;
  const int ysel = (MODE == 0) ? (blockIdx.y >> 2) : 0;
  const ushort* A = (MODE == 0) ? (ysel == 0 ? A0 : ysel == 1 ? A1 : A2) : A0;
  const ushort* W = (MODE == 0) ? (ysel == 0 ? W0 : ysel == 1 ? W1 : W2) : W0;
  const int n0 = ((MODE == 0) ? (blockIdx.y & 3) : blockIdx.y) * 256;

  // staging geometry: thread -> (row tid>>3, 16B chunk tid&7), pre-swizzled src
  const int row_r = tid >> 3;
  const int cb = ((tid & 7) * 16) ^ ((row_r & 7) << 4);
  const ushort* Asrc = A + (size_t)(m0 + row_r) * DM + (cb >> 1);
  const ushort* Wsrc = W + (size_t)(n0 + row_r) * DM + (cb >> 1);

#define STG_A(buf, kt, h)                                                     \
  { const int kq = (kt) * 64;                                                 \
    glds16(Asrc + (size_t)((h) * 128) * DM + kq, &As[buf][(h) * 8192 + w * 512]); \
    glds16(Asrc + (size_t)((h) * 128 + 64) * DM + kq,                         \
           &As[buf][(h) * 8192 + 4096 + w * 512]); }
#define STG_B(buf, kt, h)                                                     \
  { const int kq = (kt) * 64;                                                 \
    glds16(Wsrc + (size_t)((h) * 128) * DM + kq, &Bs[buf][(h) * 8192 + w * 512]); \
    glds16(Wsrc + (size_t)((h) * 128 + 64) * DM + kq,                         \
           &Bs[buf][(h) * 8192 + 4096 + w * 512]); }

  f32x4 acc[16][2] = {};
  short8 af[4][2], bf[2][2];

  // prologue: tile 0, order Bh0,Bh1,Ah0,Ah1; vmcnt(2) leaves Ah1 in flight.
  STG_B(0, 0, 0); STG_B(0, 0, 1); STG_A(0, 0, 0); STG_A(0, 0, 1);
  asm volatile("s_waitcnt vmcnt(2)" ::: "memory");
  __builtin_amdgcn_s_barrier();
  __builtin_amdgcn_sched_barrier(0);

  for (int kt = 0; kt < 16; ++kt) {
    const int buf = kt & 1;
    const int tn = kt < 15 ? kt + 1 : 15;
    const ushort* Acur = &As[buf][0];
    const ushort* Bcur = &Bs[buf][0];
#pragma unroll
    for (int p = 0; p < 4; ++p) {
      // ---- register loads from LDS (current buf) ----
      if (p == 0) {
#pragma unroll
        for (int n = 0; n < 2; n++)
#pragma unroll
          for (int kk = 0; kk < 2; kk++)
            bf[n][kk] = ldsrd(Bcur, w * 32 + n * 16 + lr, kk * 64 + g * 16);
      }
#pragma unroll
      for (int i = 0; i < 4; i++)
#pragma unroll
        for (int kk = 0; kk < 2; kk++)
          af[i][kk] = ldsrd(Acur, (4 * p + i) * 16 + lr, kk * 64 + g * 16);
      // ---- stage one half-tile of next K-tile into buf^1 ----
      if (p == 0)      { STG_B(buf ^ 1, tn, 0); }
      else if (p == 1) { STG_B(buf ^ 1, tn, 1); }
      else if (p == 2) { STG_A(buf ^ 1, tn, 0); }
      else             { STG_A(buf ^ 1, tn, 1); }
      // ---- counted vmcnt (never 0) ----
      if (p == 1) asm volatile("s_waitcnt vmcnt(4)" ::: "memory");
      if (p == 3) asm volatile("s_waitcnt vmcnt(2)" ::: "memory");
      __builtin_amdgcn_sched_barrier(0);
      __builtin_amdgcn_s_barrier();
      asm volatile("s_waitcnt lgkmcnt(0)" ::: "memory");
      __builtin_amdgcn_sched_barrier(0);
      __builtin_amdgcn_s_setprio(1);
#pragma unroll
      for (int i = 0; i < 4; i++)
#pragma unroll
        for (int n = 0; n < 2; n++)
#pragma unroll
          for (int kk = 0; kk < 2; kk++)
            acc[4 * p + i][n] = __builtin_amdgcn_mfma_f32_16x16x32_bf16(
                af[i][kk], bf[n][kk], acc[4 * p + i][n], 0, 0, 0);
      __builtin_amdgcn_s_setprio(0);
      __builtin_amdgcn_sched_barrier(0);
      __builtin_amdgcn_s_barrier();
    }
  }
#undef STG_A
#undef STG_B

  // ---- epilogue ----
  const int colB = n0 + w * 32;
#pragma unroll
  for (int m = 0; m < 16; ++m) {
    const int row0 = m0 + m * 16 + g * 4;
#pragma unroll
    for (int n = 0; n < 2; ++n) {
      const int col = colB + n * 16 + lr;
      if (MODE == 2) {
#pragma unroll
        for (int r = 0; r < 4; r++)
          reinterpret_cast<float*>(O0)[(size_t)(row0 + r) * DM + col] = acc[m][n][r];
      } else if (ysel == 0 || ysel == 1) {
        ushort* O = reinterpret_cast<ushort*>(ysel == 0 ? O0 : O1);
#pragma unroll
        for (int r = 0; r < 4; r++)
          O[(size_t)(row0 + r) * DM + col] = f2b(acc[m][n][r]);
      } else {
        // V transposed: [B][H][DH][S], 4 consecutive s -> ushort4
        const int b = row0 >> 12, s0 = row0 & 4095;
        const int h = col >> 6, dk = col & 63;
        ushort4 o;
        o.x = f2b(acc[m][n][0]); o.y = f2b(acc[m][n][1]);
        o.z = f2b(acc[m][n][2]); o.w = f2b(acc[m][n][3]);
        *reinterpret_cast<ushort4*>(
            reinterpret_cast<ushort*>(O2) +
            (((size_t)(b * NH + h) * DH + dk) << 12) + s0) = o;
      }
    }
  }
}

// ---------------- local attention (window |i-j|<=128) ----------------
__global__ void attn_local(const ushort* __restrict__ Qp, const ushort* __restrict__ Kp,
                           const ushort* __restrict__ Vt, ushort* __restrict__ Ao) {
  __shared__ ushort Ks[64 * 64];
  __shared__ ushort Vs[64 * 64];
  __shared__ ushort Ps[4][16 * 72];
  const int tid = threadIdx.x;
  const int lane = tid & 63;
  const int w = tid >> 6;
  const int g = lane >> 4, lr = lane & 15;
  const int bh = blockIdx.y, b = bh >> 4, h = bh & 15;
  const int q0 = blockIdx.x * 64;

  const int qrow = q0 + w * 16 + lr;
  const ushort* qptr = Qp + ((size_t)b * S_LEN + qrow) * DM + h * DH;
  short8 qf[2];
  qf[0] = *reinterpret_cast<const short8*>(qptr + g * 8);
  qf[1] = *reinterpret_cast<const short8*>(qptr + 32 + g * 8);

  float m_r[4], l_r[4];
  f32x4 acc_o[4] = {};
#pragma unroll
  for (int r = 0; r < 4; r++) { m_r[r] = -1e30f; l_r[r] = 0.f; }

  const int sr = tid >> 3;
  const int scb = (tid & 7) * 16;

  const int t_lo = q0 >= 128 ? q0 - 128 : 0;
  const int t_hi = (q0 + 192) <= S_LEN ? (q0 + 192) : S_LEN;

  for (int k0 = t_lo; k0 < t_hi; k0 += 64) {
    __syncthreads();
#pragma unroll
    for (int i = 0; i < 2; i++) {
      const int row = i * 32 + sr;
      const int cb = scb ^ ((row & 7) << 4);
      glds16(Kp + ((size_t)b * S_LEN + k0 + row) * DM + h * DH + cb / 2,
             Ks + i * 2048 + w * 512);
      glds16(Vt + (((size_t)bh * DH + row) << 12) + k0 + cb / 2,
             Vs + i * 2048 + w * 512);
    }
    __syncthreads();

    f32x4 sc[4] = {};
#pragma unroll
    for (int kk = 0; kk < 2; kk++) {
#pragma unroll
      for (int nt = 0; nt < 4; nt++) {
        const int kr = nt * 16 + lr;
        const int cb = (kk * 64 + g * 16) ^ ((kr & 7) << 4);
        short8 kf = *reinterpret_cast<const short8*>(
            reinterpret_cast<const char*>(Ks) + kr * 128 + cb);
        sc[nt] = __builtin_amdgcn_mfma_f32_16x16x32_bf16(qf[kk], kf, sc[nt], 0, 0, 0);
      }
    }
    float mx[4] = {-1e30f, -1e30f, -1e30f, -1e30f};
#pragma unroll
    for (int nt = 0; nt < 4; nt++) {
      const int key = k0 + nt * 16 + lr;
#pragma unroll
      for (int r = 0; r < 4; r++) {
        const int qr = q0 + w * 16 + g * 4 + r;
        int d = qr - key; d = d < 0 ? -d : d;
        float s = (d <= 128) ? sc[nt][r] * 0.125f : -1e9f;
        sc[nt][r] = s;
        mx[r] = fmaxf(mx[r], s);
      }
    }
#pragma unroll
    for (int r = 0; r < 4; r++) {
      mx[r] = fmaxf(mx[r], __shfl_xor(mx[r], 1));
      mx[r] = fmaxf(mx[r], __shfl_xor(mx[r], 2));
      mx[r] = fmaxf(mx[r], __shfl_xor(mx[r], 4));
      mx[r] = fmaxf(mx[r], __shfl_xor(mx[r], 8));
    }
    float fac[4], rs[4];
#pragma unroll
    for (int r = 0; r < 4; r++) {
      const float mn = fmaxf(m_r[r], mx[r]);
      fac[r] = __expf(m_r[r] - mn);
      m_r[r] = mn;
      rs[r] = 0.f;
    }
#pragma unroll
    for (int nt = 0; nt < 4; nt++)
#pragma unroll
      for (int r = 0; r < 4; r++) {
        const float p = __expf(sc[nt][r] - m_r[r]);
        sc[nt][r] = p;
        rs[r] += p;
      }
#pragma unroll
    for (int r = 0; r < 4; r++) {
      rs[r] += __shfl_xor(rs[r], 1);
      rs[r] += __shfl_xor(rs[r], 2);
      rs[r] += __shfl_xor(rs[r], 4);
      rs[r] += __shfl_xor(rs[r], 8);
      l_r[r] = l_r[r] * fac[r] + rs[r];
    }
#pragma unroll
    for (int nt = 0; nt < 4; nt++)
#pragma unroll
      for (int r = 0; r < 4; r++)
        acc_o[nt][r] *= fac[r];

    ushort* myP = Ps[w];
#pragma unroll
    for (int nt = 0; nt < 4; nt++)
#pragma unroll
      for (int r = 0; r < 4; r++)
        myP[(g * 4 + r) * 72 + nt * 16 + lr] = f2b(sc[nt][r]);
    asm volatile("s_waitcnt lgkmcnt(0)" ::: "memory");
    __builtin_amdgcn_sched_barrier(0);

#pragma unroll
    for (int kk = 0; kk < 2; kk++) {
      short8 pf = *reinterpret_cast<const short8*>(myP + lr * 72 + kk * 32 + g * 8);
#pragma unroll
      for (int nt = 0; nt < 4; nt++) {
        const int vr = nt * 16 + lr;
        const int cb = (kk * 64 + g * 16) ^ ((vr & 7) << 4);
        short8 vf = *reinterpret_cast<const short8*>(
            reinterpret_cast<const char*>(Vs) + vr * 128 + cb);
        acc_o[nt] = __builtin_amdgcn_mfma_f32_16x16x32_bf16(pf, vf, acc_o[nt], 0, 0, 0);
      }
    }
  }

  const int qr0 = q0 + w * 16 + g * 4;
  ushort* orow = Ao + (size_t)b * S_LEN * DM + h * DH;
#pragma unroll
  for (int nt = 0; nt < 4; nt++)
#pragma unroll
    for (int r = 0; r < 4; r++)
      orow[(size_t)(qr0 + r) * DM + nt * 16 + lr] = f2b(acc_o[nt][r] / l_r[r]);
}

extern "C" void kernel_launch(void* const* d_in, const int* in_sizes, int n_in,
                              void* d_out, int out_size, void* d_ws, size_t ws_size,
                              hipStream_t stream) {
  const float* q  = (const float*)d_in[0];
  const float* k  = (const float*)d_in[1];
  const float* v  = (const float*)d_in[2];
  const float* wq = (const float*)d_in[3];
  const float* wk = (const float*)d_in[4];
  const float* wv = (const float*)d_in[5];
  const float* wo = (const float*)d_in[6];

  const size_t NX = (size_t)B_SZ * S_LEN * DM;  // 8388608
  const size_t NW = (size_t)DM * DM;            // 1048576
  if (ws_size < (7 * NX + 4 * NW) * sizeof(ushort)) return;

  ushort* ws  = (ushort*)d_ws;
  ushort* qb  = ws;
  ushort* kb  = qb + NX;
  ushort* vb  = kb + NX;
  ushort* wqb = vb + NX;
  ushort* wkb = wqb + NW;
  ushort* wvb = wkb + NW;
  ushort* wob = wvb + NW;
  ushort* Qp  = wob + NW;
  ushort* Kp  = Qp + NX;
  ushort* Vt  = Kp + NX;
  ushort* Ao  = Vt + NX;

  cvt_all<<<dim3(2048), dim3(256), 0, stream>>>(q, k, v, wq, wk, wv, wo, ws);

  gemm8<0><<<dim3(32, 12), dim3(512), 0, stream>>>(qb, kb, vb, wqb, wkb, wvb,
                                                   Qp, Kp, Vt);

  attn_local<<<dim3(64, 32), dim3(256), 0, stream>>>(Qp, Kp, Vt, Ao);

  gemm8<2><<<dim3(32, 4), dim3(512), 0, stream>>>(Ao, Ao, Ao, wob, wob, wob,
                                                  d_out, d_out, d_out);
}

// Round 4
// 154.847 us; speedup vs baseline: 1.2317x; 1.1211x over previous
//
#include <hip/hip_runtime.h>
#include <hip/hip_bf16.h>

#define S_LEN 4096
#define B_SZ 2
#define DM 1024
#define NH 16
#define DH 64

typedef __attribute__((ext_vector_type(8))) short short8;
typedef __attribute__((ext_vector_type(4))) float f32x4;

__device__ __forceinline__ ushort f2b(float f) {
  union { __hip_bfloat16 b; ushort u; } cv;
  cv.b = __float2bfloat16(f);
  return cv.u;
}

__device__ __forceinline__ void glds16(const ushort* g, ushort* l) {
  __builtin_amdgcn_global_load_lds(
      (const __attribute__((address_space(1))) void*)g,
      (__attribute__((address_space(3))) void*)l, 16, 0, 0);
}

// ---------------- merged fp32 -> bf16 convert ----------------
__global__ void cvt_all(const float* __restrict__ q, const float* __restrict__ k,
                        const float* __restrict__ v, const float* __restrict__ wq,
                        const float* __restrict__ wk, const float* __restrict__ wv,
                        const float* __restrict__ wo, ushort* __restrict__ dst) {
  const int NX4 = 2097152;  // 8M/4
  const int NW4 = 262144;   // 1M/4
  const int total = 3 * NX4 + 4 * NW4;
  for (int i = blockIdx.x * blockDim.x + threadIdx.x; i < total;
       i += gridDim.x * blockDim.x) {
    const float* s;
    int j;
    if (i < NX4) { s = q; j = i; }
    else if (i < 2 * NX4) { s = k; j = i - NX4; }
    else if (i < 3 * NX4) { s = v; j = i - 2 * NX4; }
    else {
      int t = i - 3 * NX4;
      int wsel = t >> 18;
      j = t & (NW4 - 1);
      s = wsel == 0 ? wq : wsel == 1 ? wk : wsel == 2 ? wv : wo;
    }
    float4 val = reinterpret_cast<const float4*>(s)[j];
    ushort4 o;
    o.x = f2b(val.x); o.y = f2b(val.y); o.z = f2b(val.z); o.w = f2b(val.w);
    reinterpret_cast<ushort4*>(dst)[i] = o;
  }
}

// swizzled LDS read: XOR row bits 0-2 into byte-col bits 4-6
__device__ __forceinline__ short8 ldsrd(const ushort* base, int row, int cb) {
  const int pcb = cb ^ ((row & 7) << 4);
  return *reinterpret_cast<const short8*>(
      reinterpret_cast<const char*>(base) + row * 128 + pcb);
}

// ---------------- 3-deep pipelined bt-GEMM ----------------
// C[m][n] = sum_k A[m][k]*W[n][k].  BM=256, BN=128, BK=64, 512 threads.
// 8 waves (wm=w>>1 in 0..3, wn=w&1), per-wave 64x64 output.
// 3 LDS buffers; iteration kt reads buf kt%3, stages tile kt+2 into (kt+2)%3.
// ONE barrier + ONE vmcnt(6) per K-tile (never drains below 6): the tile
// being waited on was staged 2 iterations (~2.5k cyc) earlier.
// MODE 0: QKV fused (blockIdx.y>>3 selects mat; V written transposed).
// MODE 2: f32 out.
template <int MODE>
__launch_bounds__(512, 2)
__global__ void gemmP(const ushort* __restrict__ A0, const ushort* __restrict__ A1,
                      const ushort* __restrict__ A2, const ushort* __restrict__ W0,
                      const ushort* __restrict__ W1, const ushort* __restrict__ W2,
                      void* __restrict__ O0, void* __restrict__ O1,
                      void* __restrict__ O2) {
  __shared__ ushort As[3][16384];  // 256x64 each, 96 KB
  __shared__ ushort Bs[3][8192];   // 128x64 each, 48 KB
  const int tid = threadIdx.x;
  const int lane = tid & 63, w = tid >> 6;
  const int wm = w >> 1, wn = w & 1;
  const int g = lane >> 4, lr = lane & 15;
  const int m0 = blockIdx.x * 256;
  const int ysel = (MODE == 0) ? (blockIdx.y >> 3) : 0;
  const ushort* A = (MODE == 0) ? (ysel == 0 ? A0 : ysel == 1 ? A1 : A2) : A0;
  const ushort* W = (MODE == 0) ? (ysel == 0 ? W0 : ysel == 1 ? W1 : W2) : W0;
  const int n0 = ((MODE == 0) ? (blockIdx.y & 7) : blockIdx.y) * 128;

  // staging geometry: thread -> (row tid>>3, 16B chunk tid&7), pre-swizzled src
  const int row_r = tid >> 3;
  const int cb = ((tid & 7) * 16) ^ ((row_r & 7) << 4);
  const ushort* Asrc = A + (size_t)(m0 + row_r) * DM + (cb >> 1);
  const ushort* Wsrc = W + (size_t)(n0 + row_r) * DM + (cb >> 1);

  // A: 4 segments of 64 rows; B: 2 segments. 6 loads/thread per K-tile.
#define STG_A012(bs, kt)                                                     \
  { const int kq = (kt) * 64;                                                \
    glds16(Asrc + kq,                        &As[bs][w * 512]);              \
    glds16(Asrc + (size_t)64 * DM + kq,      &As[bs][4096 + w * 512]);       \
    glds16(Asrc + (size_t)128 * DM + kq,     &As[bs][8192 + w * 512]); }
#define STG_A3B01(bs, kt)                                                    \
  { const int kq = (kt) * 64;                                                \
    glds16(Asrc + (size_t)192 * DM + kq,     &As[bs][12288 + w * 512]);      \
    glds16(Wsrc + kq,                        &Bs[bs][w * 512]);              \
    glds16(Wsrc + (size_t)64 * DM + kq,      &Bs[bs][4096 + w * 512]); }

  f32x4 acc[4][4] = {};
  short8 af[4][2], bf[2][2];

  // prologue: tile0 -> buf0, tile1 -> buf1 (12 loads outstanding)
  STG_A012(0, 0); STG_A3B01(0, 0);
  STG_A012(1, 1); STG_A3B01(1, 1);

  int bc = 0;
  for (int kt = 0; kt < 16; ++kt) {
    const int bs = bc >= 1 ? bc - 1 : bc + 2;  // (bc+2)%3
    const int tn = kt + 2 < 16 ? kt + 2 : 15;
    asm volatile("s_waitcnt vmcnt(6)" ::: "memory");
    __builtin_amdgcn_s_barrier();
    __builtin_amdgcn_sched_barrier(0);
    const ushort* Ab = &As[bc][0];
    const ushort* Bb = &Bs[bc][0];
    // ---- sub-phase 0: A-frags + B-frags n0/n1; stage A segs 0-2 ----
#pragma unroll
    for (int m = 0; m < 4; m++)
#pragma unroll
      for (int kk = 0; kk < 2; kk++)
        af[m][kk] = ldsrd(Ab, wm * 64 + m * 16 + lr, kk * 64 + g * 16);
#pragma unroll
    for (int n = 0; n < 2; n++)
#pragma unroll
      for (int kk = 0; kk < 2; kk++)
        bf[n][kk] = ldsrd(Bb, wn * 64 + n * 16 + lr, kk * 64 + g * 16);
    STG_A012(bs, tn);
    __builtin_amdgcn_sched_barrier(0);
    asm volatile("s_waitcnt lgkmcnt(0)" ::: "memory");
    __builtin_amdgcn_sched_barrier(0);
    __builtin_amdgcn_s_setprio(1);
#pragma unroll
    for (int m = 0; m < 4; m++)
#pragma unroll
      for (int n = 0; n < 2; n++)
#pragma unroll
        for (int kk = 0; kk < 2; kk++)
          acc[m][n] = __builtin_amdgcn_mfma_f32_16x16x32_bf16(af[m][kk], bf[n][kk],
                                                              acc[m][n], 0, 0, 0);
    __builtin_amdgcn_s_setprio(0);
    __builtin_amdgcn_sched_barrier(0);
    // ---- sub-phase 1: B-frags n2/n3; stage A seg 3 + B segs 0-1 ----
#pragma unroll
    for (int n = 0; n < 2; n++)
#pragma unroll
      for (int kk = 0; kk < 2; kk++)
        bf[n][kk] = ldsrd(Bb, wn * 64 + 32 + n * 16 + lr, kk * 64 + g * 16);
    STG_A3B01(bs, tn);
    __builtin_amdgcn_sched_barrier(0);
    asm volatile("s_waitcnt lgkmcnt(0)" ::: "memory");
    __builtin_amdgcn_sched_barrier(0);
    __builtin_amdgcn_s_setprio(1);
#pragma unroll
    for (int m = 0; m < 4; m++)
#pragma unroll
      for (int n = 0; n < 2; n++)
#pragma unroll
        for (int kk = 0; kk < 2; kk++)
          acc[m][2 + n] = __builtin_amdgcn_mfma_f32_16x16x32_bf16(af[m][kk], bf[n][kk],
                                                                  acc[m][2 + n], 0, 0, 0);
    __builtin_amdgcn_s_setprio(0);
    __builtin_amdgcn_sched_barrier(0);
    bc = bc + 1 == 3 ? 0 : bc + 1;
  }
#undef STG_A012
#undef STG_A3B01

  // ---- epilogue ----
  const int colB = n0 + wn * 64;
#pragma unroll
  for (int m = 0; m < 4; ++m) {
    const int row0 = m0 + wm * 64 + m * 16 + g * 4;
#pragma unroll
    for (int n = 0; n < 4; ++n) {
      const int col = colB + n * 16 + lr;
      if (MODE == 2) {
#pragma unroll
        for (int r = 0; r < 4; r++)
          reinterpret_cast<float*>(O0)[(size_t)(row0 + r) * DM + col] = acc[m][n][r];
      } else if (ysel == 0 || ysel == 1) {
        ushort* O = reinterpret_cast<ushort*>(ysel == 0 ? O0 : O1);
#pragma unroll
        for (int r = 0; r < 4; r++)
          O[(size_t)(row0 + r) * DM + col] = f2b(acc[m][n][r]);
      } else {
        // V transposed: [B][H][DH][S], 4 consecutive s -> ushort4
        const int b = row0 >> 12, s0 = row0 & 4095;
        const int h = col >> 6, dk = col & 63;
        ushort4 o;
        o.x = f2b(acc[m][n][0]); o.y = f2b(acc[m][n][1]);
        o.z = f2b(acc[m][n][2]); o.w = f2b(acc[m][n][3]);
        *reinterpret_cast<ushort4*>(
            reinterpret_cast<ushort*>(O2) +
            (((size_t)(b * NH + h) * DH + dk) << 12) + s0) = o;
      }
    }
  }
}

// ---------------- local attention (window |i-j|<=128) ----------------
__global__ void attn_local(const ushort* __restrict__ Qp, const ushort* __restrict__ Kp,
                           const ushort* __restrict__ Vt, ushort* __restrict__ Ao) {
  __shared__ ushort Ks[64 * 64];
  __shared__ ushort Vs[64 * 64];
  __shared__ ushort Ps[4][16 * 72];
  const int tid = threadIdx.x;
  const int lane = tid & 63;
  const int w = tid >> 6;
  const int g = lane >> 4, lr = lane & 15;
  const int bh = blockIdx.y, b = bh >> 4, h = bh & 15;
  const int q0 = blockIdx.x * 64;

  const int qrow = q0 + w * 16 + lr;
  const ushort* qptr = Qp + ((size_t)b * S_LEN + qrow) * DM + h * DH;
  short8 qf[2];
  qf[0] = *reinterpret_cast<const short8*>(qptr + g * 8);
  qf[1] = *reinterpret_cast<const short8*>(qptr + 32 + g * 8);

  float m_r[4], l_r[4];
  f32x4 acc_o[4] = {};
#pragma unroll
  for (int r = 0; r < 4; r++) { m_r[r] = -1e30f; l_r[r] = 0.f; }

  const int sr = tid >> 3;
  const int scb = (tid & 7) * 16;

  const int t_lo = q0 >= 128 ? q0 - 128 : 0;
  const int t_hi = (q0 + 192) <= S_LEN ? (q0 + 192) : S_LEN;

  for (int k0 = t_lo; k0 < t_hi; k0 += 64) {
    __syncthreads();
#pragma unroll
    for (int i = 0; i < 2; i++) {
      const int row = i * 32 + sr;
      const int cb = scb ^ ((row & 7) << 4);
      glds16(Kp + ((size_t)b * S_LEN + k0 + row) * DM + h * DH + cb / 2,
             Ks + i * 2048 + w * 512);
      glds16(Vt + (((size_t)bh * DH + row) << 12) + k0 + cb / 2,
             Vs + i * 2048 + w * 512);
    }
    __syncthreads();

    f32x4 sc[4] = {};
#pragma unroll
    for (int kk = 0; kk < 2; kk++) {
#pragma unroll
      for (int nt = 0; nt < 4; nt++) {
        const int kr = nt * 16 + lr;
        const int cb = (kk * 64 + g * 16) ^ ((kr & 7) << 4);
        short8 kf = *reinterpret_cast<const short8*>(
            reinterpret_cast<const char*>(Ks) + kr * 128 + cb);
        sc[nt] = __builtin_amdgcn_mfma_f32_16x16x32_bf16(qf[kk], kf, sc[nt], 0, 0, 0);
      }
    }
    float mx[4] = {-1e30f, -1e30f, -1e30f, -1e30f};
#pragma unroll
    for (int nt = 0; nt < 4; nt++) {
      const int key = k0 + nt * 16 + lr;
#pragma unroll
      for (int r = 0; r < 4; r++) {
        const int qr = q0 + w * 16 + g * 4 + r;
        int d = qr - key; d = d < 0 ? -d : d;
        float s = (d <= 128) ? sc[nt][r] * 0.125f : -1e9f;
        sc[nt][r] = s;
        mx[r] = fmaxf(mx[r], s);
      }
    }
#pragma unroll
    for (int r = 0; r < 4; r++) {
      mx[r] = fmaxf(mx[r], __shfl_xor(mx[r], 1));
      mx[r] = fmaxf(mx[r], __shfl_xor(mx[r], 2));
      mx[r] = fmaxf(mx[r], __shfl_xor(mx[r], 4));
      mx[r] = fmaxf(mx[r], __shfl_xor(mx[r], 8));
    }
    float fac[4], rs[4];
#pragma unroll
    for (int r = 0; r < 4; r++) {
      const float mn = fmaxf(m_r[r], mx[r]);
      fac[r] = __expf(m_r[r] - mn);
      m_r[r] = mn;
      rs[r] = 0.f;
    }
#pragma unroll
    for (int nt = 0; nt < 4; nt++)
#pragma unroll
      for (int r = 0; r < 4; r++) {
        const float p = __expf(sc[nt][r] - m_r[r]);
        sc[nt][r] = p;
        rs[r] += p;
      }
#pragma unroll
    for (int r = 0; r < 4; r++) {
      rs[r] += __shfl_xor(rs[r], 1);
      rs[r] += __shfl_xor(rs[r], 2);
      rs[r] += __shfl_xor(rs[r], 4);
      rs[r] += __shfl_xor(rs[r], 8);
      l_r[r] = l_r[r] * fac[r] + rs[r];
    }
#pragma unroll
    for (int nt = 0; nt < 4; nt++)
#pragma unroll
      for (int r = 0; r < 4; r++)
        acc_o[nt][r] *= fac[r];

    ushort* myP = Ps[w];
#pragma unroll
    for (int nt = 0; nt < 4; nt++)
#pragma unroll
      for (int r = 0; r < 4; r++)
        myP[(g * 4 + r) * 72 + nt * 16 + lr] = f2b(sc[nt][r]);
    asm volatile("s_waitcnt lgkmcnt(0)" ::: "memory");
    __builtin_amdgcn_sched_barrier(0);

#pragma unroll
    for (int kk = 0; kk < 2; kk++) {
      short8 pf = *reinterpret_cast<const short8*>(myP + lr * 72 + kk * 32 + g * 8);
#pragma unroll
      for (int nt = 0; nt < 4; nt++) {
        const int vr = nt * 16 + lr;
        const int cb = (kk * 64 + g * 16) ^ ((vr & 7) << 4);
        short8 vf = *reinterpret_cast<const short8*>(
            reinterpret_cast<const char*>(Vs) + vr * 128 + cb);
        acc_o[nt] = __builtin_amdgcn_mfma_f32_16x16x32_bf16(pf, vf, acc_o[nt], 0, 0, 0);
      }
    }
  }

  const int qr0 = q0 + w * 16 + g * 4;
  ushort* orow = Ao + (size_t)b * S_LEN * DM + h * DH;
#pragma unroll
  for (int nt = 0; nt < 4; nt++)
#pragma unroll
    for (int r = 0; r < 4; r++)
      orow[(size_t)(qr0 + r) * DM + nt * 16 + lr] = f2b(acc_o[nt][r] / l_r[r]);
}

extern "C" void kernel_launch(void* const* d_in, const int* in_sizes, int n_in,
                              void* d_out, int out_size, void* d_ws, size_t ws_size,
                              hipStream_t stream) {
  const float* q  = (const float*)d_in[0];
  const float* k  = (const float*)d_in[1];
  const float* v  = (const float*)d_in[2];
  const float* wq = (const float*)d_in[3];
  const float* wk = (const float*)d_in[4];
  const float* wv = (const float*)d_in[5];
  const float* wo = (const float*)d_in[6];

  const size_t NX = (size_t)B_SZ * S_LEN * DM;  // 8388608
  const size_t NW = (size_t)DM * DM;            // 1048576
  if (ws_size < (7 * NX + 4 * NW) * sizeof(ushort)) return;

  ushort* ws  = (ushort*)d_ws;
  ushort* qb  = ws;
  ushort* kb  = qb + NX;
  ushort* vb  = kb + NX;
  ushort* wqb = vb + NX;
  ushort* wkb = wqb + NW;
  ushort* wvb = wkb + NW;
  ushort* wob = wvb + NW;
  ushort* Qp  = wob + NW;
  ushort* Kp  = Qp + NX;
  ushort* Vt  = Kp + NX;
  ushort* Ao  = Vt + NX;

  cvt_all<<<dim3(2048), dim3(256), 0, stream>>>(q, k, v, wq, wk, wv, wo, ws);

  gemmP<0><<<dim3(32, 24), dim3(512), 0, stream>>>(qb, kb, vb, wqb, wkb, wvb,
                                                   Qp, Kp, Vt);

  attn_local<<<dim3(64, 32), dim3(256), 0, stream>>>(Qp, Kp, Vt, Ao);

  gemmP<2><<<dim3(32, 8), dim3(512), 0, stream>>>(Ao, Ao, Ao, wob, wob, wob,
                                                  d_out, d_out, d_out);
}